// Round 15
// baseline (1384.141 us; speedup 1.0000x reference)
//
#include <hip/hip_runtime.h>
#include <cstdint>

#define N_PTS   8192
#define N_BATCH 8
#define NPOINT  2048
#define NSAMPLE 32
#define C_FEAT  64
#define R2      0.04f
#define FPS_T   1024
#define CH      (N_PTS / FPS_T)   // 8 points per thread = one chunk
#define NBINS   512               // 9-bit morton (3 bits/axis)
#define NWAVE   (FPS_T / 64)      // 16

static __device__ __forceinline__ uint32_t spread3(uint32_t v) {
  return (v & 1u) | ((v & 2u) << 2) | ((v & 4u) << 4);
}

static __device__ __forceinline__ uint32_t cell_of(float x, float y, float z) {
  int ix = (int)(x * 8.0f); ix = ix < 0 ? 0 : (ix > 7 ? 7 : ix);
  int iy = (int)(y * 8.0f); iy = iy < 0 ? 0 : (iy > 7 ? 7 : iy);
  int iz = (int)(z * 8.0f); iz = iz < 0 ? 0 : (iz > 7 ? 7 : iz);
  return spread3((uint32_t)ix) | (spread3((uint32_t)iy) << 1) | (spread3((uint32_t)iz) << 2);
}

// Wave-max step on packed positive f64 key via DPP (validated R2/R3/R6-R14).
#define DPP_MAXD(v, CTRL) do {                                                          \
  uint64_t u_ = __builtin_bit_cast(uint64_t, v);                                        \
  int lo_ = __builtin_amdgcn_update_dpp(0, (int)(uint32_t)u_,         CTRL, 0xF, 0xF, true); \
  int hi_ = __builtin_amdgcn_update_dpp(0, (int)(uint32_t)(u_ >> 32), CTRL, 0xF, 0xF, true); \
  double p_ = __builtin_bit_cast(double, ((uint64_t)(uint32_t)hi_ << 32) | (uint64_t)(uint32_t)lo_); \
  v = __builtin_fmax(v, p_);                                                            \
} while (0)

// ---------------------------------------------------------------------------
// FPS, one block per batch. R8 structure VERBATIM (measured optimum 1306 us)
// + ONE change: s_setprio(1) around the active-wave path. The straggler wave
// (the one whose lanes update) shares its SIMD with up to 3 skip-waves;
// default round-robin arbitration stretches its ~460-cyc serial path 2-4x.
// Raising its priority compresses the block's critical chain; skip waves
// fill the vacated slots before their barrier wait. No semantic change.
// Retired by measurement: coord-carry (R9), transpose (R10), 8-wave (R11),
// 4096-sort (R12), fmed3 (R13).
// ---------------------------------------------------------------------------
__global__ __launch_bounds__(FPS_T) void fps_kernel(const float* __restrict__ xyz,
                                                    float* __restrict__ new_xyz) {
  __shared__ float sx[N_PTS], sy[N_PTS], sz[N_PTS];
  __shared__ int perm[N_PTS];          // setup only; reused as cent[] in loop
  __shared__ uint32_t bins[NBINS];
  __shared__ double pkey[2][NWAVE];
  float* cent = (float*)perm;          // [NPOINT*3] = 24 KB < 32 KB

  const int b = blockIdx.x;
  const int t = threadIdx.x;
  const int lane = t & 63;
  const int w = t >> 6;
  const float* xb = xyz + (size_t)b * N_PTS * 3;

  // ---- setup: stage coords ----
  for (int e = t; e < N_PTS * 3; e += FPS_T) {
    float v = xb[e];
    int p = e / 3, c = e - 3 * p;
    if (c == 0) sx[p] = v;
    else if (c == 1) sy[p] = v;
    else sz[p] = v;
  }
  if (t < NBINS) bins[t] = 0;
  __syncthreads();

  // ---- counting sort by morton cell: histogram ----
#pragma unroll
  for (int k = 0; k < CH; ++k) {
    int p = k * FPS_T + t;
    atomicAdd(&bins[cell_of(sx[p], sy[p], sz[p])], 1u);
  }
  __syncthreads();

  // ---- exclusive scan of 512 bins (wave 0, in place) ----
  if (t < 64) {
    uint32_t v[8], e[8], run = 0;
#pragma unroll
    for (int j = 0; j < 8; ++j) v[j] = bins[t * 8 + j];
#pragma unroll
    for (int j = 0; j < 8; ++j) { e[j] = run; run += v[j]; }
    uint32_t inc = run;
#pragma unroll
    for (int off = 1; off < 64; off <<= 1) {
      uint32_t o = __shfl_up(inc, off, 64);
      if (t >= off) inc += o;
    }
    uint32_t base = inc - run;
#pragma unroll
    for (int j = 0; j < 8; ++j) bins[t * 8 + j] = base + e[j];
  }
  __syncthreads();

  // ---- scatter permutation ----
#pragma unroll
  for (int k = 0; k < CH; ++k) {
    int p = k * FPS_T + t;
    uint32_t pos = atomicAdd(&bins[cell_of(sx[p], sy[p], sz[p])], 1u);
    perm[pos] = p;
  }
  __syncthreads();

  // ---- load chunk into registers (c = t: Morton-concentrated), bbox ----
  float rx[CH], ry[CH], rz[CH], dist[CH];
  uint32_t ridx[CH];
#pragma unroll
  for (int j = 0; j < CH; ++j) {
    int p = perm[CH * t + j];
    ridx[j] = (uint32_t)p;
    rx[j] = sx[p]; ry[j] = sy[p]; rz[j] = sz[p];
    dist[j] = __builtin_inff();
  }
  float bnx = rx[0], bxx = rx[0], bny = ry[0], bxy = ry[0], bnz = rz[0], bxz = rz[0];
#pragma unroll
  for (int j = 1; j < CH; ++j) {
    bnx = fminf(bnx, rx[j]); bxx = fmaxf(bxx, rx[j]);
    bny = fminf(bny, ry[j]); bxy = fmaxf(bxy, ry[j]);
    bnz = fminf(bnz, rz[j]); bxz = fmaxf(bxz, rz[j]);
  }
  __syncthreads();   // perm fully consumed; cent alias is now safe

  float cmax = __builtin_inff();   // chunk max dist (cached)
  uint32_t cidx = 0;               // chunk argmax orig idx (cached)
  double wkey = 0.0;               // cached wave-reduced key (lane 63 valid)
  int far = 0;

  for (int it = 0; it < NPOINT; ++it) {
    float cx = sx[far], cy = sy[far], cz = sz[far];
    if (t == 0) {   // LDS staging only -- no global store in the loop
      cent[it * 3 + 0] = cx;
      cent[it * 3 + 1] = cy;
      cent[it * 3 + 2] = cz;
    }

    // conservative lower bound of any d2 in this chunk (margin 1e-5 >> fp err)
    float gx = fmaxf(fmaxf(bnx - cx, cx - bxx), 0.0f);
    float gy = fmaxf(fmaxf(bny - cy, cy - bxy), 0.0f);
    float gz = fmaxf(fmaxf(bnz - cz, cz - bxz), 0.0f);
    float lb = gx * gx + gy * gy + gz * gz;

    bool act = !(lb * 0.99999f >= cmax);
    uint64_t am = __ballot(act);
    if (am != 0) {     // wave-uniform: this wave is on the critical path
      __builtin_amdgcn_s_setprio(1);   // win issue arbitration vs skip-waves
      if (act) {
        {
#pragma clang fp contract(off)
#pragma unroll
          for (int j = 0; j < CH; ++j) {
            float dx = rx[j] - cx;
            float a = dx * dx;
            float dy = ry[j] - cy;
            a = a + dy * dy;         // exact left-to-right, no FMA
            float dz = rz[j] - cz;
            a = a + dz * dz;
            dist[j] = fminf(dist[j], a);
          }
        }
        // chunk max (tree) + first-occurrence (min orig idx) tie resolution
        float m0 = fmaxf(dist[0], dist[1]), m1 = fmaxf(dist[2], dist[3]);
        float m2 = fmaxf(dist[4], dist[5]), m3 = fmaxf(dist[6], dist[7]);
        cmax = fmaxf(fmaxf(m0, m1), fmaxf(m2, m3));
        uint32_t mi = 0xFFFFFFFFu;
#pragma unroll
        for (int j = 0; j < CH; ++j) {
          uint32_t cand = ridx[j] < mi ? ridx[j] : mi;
          mi = (dist[j] == cmax) ? cand : mi;
        }
        cidx = mi;
      }
      // wave reduce over ALL lanes' cached keys (active lanes just updated)
      double key = __builtin_bit_cast(double,
          ((uint64_t)__builtin_bit_cast(uint32_t, cmax) << 32) |
          (uint64_t)(0xFFFFFFFFu - cidx));
      DPP_MAXD(key, 0x111);   // row_shr 1
      DPP_MAXD(key, 0x112);   // row_shr 2
      DPP_MAXD(key, 0x114);   // row_shr 4
      DPP_MAXD(key, 0x118);   // row_shr 8
      DPP_MAXD(key, 0x142);   // row_bcast 15
      DPP_MAXD(key, 0x143);   // row_bcast 31  -> lane 63 has wave max
      wkey = key;             // cache (lane 63's copy is the wave max)
      __builtin_amdgcn_s_setprio(0);   // back to default before the barrier
    }
    if (lane == 63) pkey[it & 1][w] = wkey;
    __syncthreads();

    // lane-parallel cross-wave reduce: lane reads slot (lane&15); 4-step DPP
    // row-reduce puts the max of all 16 slots in lane 15 of every row.
    double g = pkey[it & 1][lane & 15];
    DPP_MAXD(g, 0x111);
    DPP_MAXD(g, 0x112);
    DPP_MAXD(g, 0x114);
    DPP_MAXD(g, 0x118);
    uint64_t gu = __builtin_bit_cast(uint64_t, g);
    uint32_t glo = (uint32_t)__builtin_amdgcn_readlane((int)(uint32_t)gu, 15);
    far = (int)(0xFFFFFFFFu - glo);
  }

  // ---- one-time coalesced copy-out of staged centroids ----
  __syncthreads();
  float* ob = new_xyz + (size_t)b * NPOINT * 3;
  for (int e = t; e < NPOINT * 3; e += FPS_T) ob[e] = cent[e];
}

// ---------------------------------------------------------------------------
// Ball query + gather + concat, one wave per query (R14-verified, float2
// stores, bit-identical output).
// ---------------------------------------------------------------------------
__global__ __launch_bounds__(256) void ball_group_kernel(const float* __restrict__ xyz,
                                                         const float* __restrict__ points,
                                                         const float* __restrict__ new_xyz,
                                                         float* __restrict__ out_np) {
  __shared__ int list[4][NSAMPLE];
  const int wslot = threadIdx.x >> 6;
  const int lane = threadIdx.x & 63;
  const int qg = blockIdx.x * 4 + wslot;
  const int b = qg >> 11;

  const float* xb = xyz + (size_t)b * N_PTS * 3;
  const float* nq = new_xyz + (size_t)qg * 3;
  const float cqx = nq[0], cqy = nq[1], cqz = nq[2];

  int K = 0;
  {
#pragma clang fp contract(off)
    for (int c = 0; c < N_PTS / 64; ++c) {
      const int pt = c * 64 + lane;
      const float* p = xb + pt * 3;
      float dx = cqx - p[0];
      float dy = cqy - p[1];
      float dz = cqz - p[2];
      float d2 = dx * dx;
      d2 = d2 + dy * dy;
      d2 = d2 + dz * dz;
      bool in = d2 < R2;
      unsigned long long mask = __ballot(in);
      if (in) {
        int rank = __builtin_amdgcn_mbcnt_hi((uint32_t)(mask >> 32),
                     __builtin_amdgcn_mbcnt_lo((uint32_t)mask, 0));
        int s = K + rank;
        if (s < NSAMPLE) list[wslot][s] = pt;
      }
      K += (int)__popcll(mask);
      if (K >= NSAMPLE) break;   // wave-uniform
    }
  }
  __builtin_amdgcn_wave_barrier();
  int Kc = K < NSAMPLE ? K : NSAMPLE;
  int first = list[wslot][0];
  if (lane >= Kc && lane < NSAMPLE) list[wslot][lane] = first;
  __builtin_amdgcn_wave_barrier();

  const float* pb = points + (size_t)b * N_PTS * C_FEAT;
  float* oq = out_np + (size_t)qg * (NSAMPLE * 67);
#pragma unroll
  for (int r = 0; r < 17; ++r) {
    int pp = r * 64 + lane;                 // float2 index, 0..1071 valid
    if (pp < (NSAMPLE * 67) / 2) {
      int e0 = pp * 2;
      int s0 = e0 / 67;
      int f0 = e0 - s0 * 67;
      int s1 = (f0 == 66) ? s0 + 1 : s0;    // e1 = e0+1 may cross slot
      int f1 = (f0 == 66) ? 0 : f0 + 1;
      int i0 = list[wslot][s0];
      int i1 = list[wslot][s1];
      float v0, v1;
      if (f0 < 3) {
        float cf = (f0 == 0) ? cqx : ((f0 == 1) ? cqy : cqz);
        v0 = xb[i0 * 3 + f0] - cf;
      } else {
        v0 = pb[(size_t)i0 * C_FEAT + (f0 - 3)];
      }
      if (f1 < 3) {
        float cf = (f1 == 0) ? cqx : ((f1 == 1) ? cqy : cqz);
        v1 = xb[i1 * 3 + f1] - cf;
      } else {
        v1 = pb[(size_t)i1 * C_FEAT + (f1 - 3)];
      }
      *reinterpret_cast<float2*>(&oq[e0]) = make_float2(v0, v1);
    }
  }
}

extern "C" void kernel_launch(void* const* d_in, const int* in_sizes, int n_in,
                              void* d_out, int out_size, void* d_ws, size_t ws_size,
                              hipStream_t stream) {
  const float* xyz = (const float*)d_in[0];
  const float* points = (const float*)d_in[1];
  float* out = (float*)d_out;
  float* new_xyz = out;
  float* new_points = out + (size_t)N_BATCH * NPOINT * 3;

  fps_kernel<<<N_BATCH, FPS_T, 0, stream>>>(xyz, new_xyz);
  ball_group_kernel<<<(N_BATCH * NPOINT) / 4, 256, 0, stream>>>(xyz, points, new_xyz, new_points);
}

// Round 16
// 1371.092 us; speedup vs baseline: 1.0095x; 1.0095x over previous
//
#include <hip/hip_runtime.h>
#include <cstdint>

#define N_PTS   8192
#define N_BATCH 8
#define NPOINT  2048
#define NSAMPLE 32
#define C_FEAT  64
#define R2      0.04f
#define FPS_T   1024
#define CH      (N_PTS / FPS_T)   // 8 points per thread = one chunk
#define NBINS   512               // 9-bit morton (3 bits/axis)
#define NWAVE   (FPS_T / 64)      // 16

static __device__ __forceinline__ uint32_t spread3(uint32_t v) {
  return (v & 1u) | ((v & 2u) << 2) | ((v & 4u) << 4);
}

static __device__ __forceinline__ uint32_t cell_of(float x, float y, float z) {
  int ix = (int)(x * 8.0f); ix = ix < 0 ? 0 : (ix > 7 ? 7 : ix);
  int iy = (int)(y * 8.0f); iy = iy < 0 ? 0 : (iy > 7 ? 7 : iy);
  int iz = (int)(z * 8.0f); iz = iz < 0 ? 0 : (iz > 7 ? 7 : iz);
  return spread3((uint32_t)ix) | (spread3((uint32_t)iy) << 1) | (spread3((uint32_t)iz) << 2);
}

// Wave-max step on packed positive f64 key via DPP (validated R2-R15).
#define DPP_MAXD(v, CTRL) do {                                                          \
  uint64_t u_ = __builtin_bit_cast(uint64_t, v);                                        \
  int lo_ = __builtin_amdgcn_update_dpp(0, (int)(uint32_t)u_,         CTRL, 0xF, 0xF, true); \
  int hi_ = __builtin_amdgcn_update_dpp(0, (int)(uint32_t)(u_ >> 32), CTRL, 0xF, 0xF, true); \
  double p_ = __builtin_bit_cast(double, ((uint64_t)(uint32_t)hi_ << 32) | (uint64_t)(uint32_t)lo_); \
  v = __builtin_fmax(v, p_);                                                            \
} while (0)

// ---------------------------------------------------------------------------
// FPS, one block per batch — R8 VERBATIM, the measured optimum (1306 us).
// Structure: Morton counting-sort into 8-point register chunks (c = t keeps
// the hot set concentrated in few waves), exact bbox pruning (1e-5 margin),
// wave-level skip via ballot, f32 dist state + fmax tree + first-occurrence
// tie scan, packed f64 key (d2bits<<32)|~idx, 6-step DPP wave reduce,
// parity-buffered per-wave slots, lane-parallel 4-step cross-wave reduce,
// LDS-staged centroid output (no global ops in the loop).
// Retired by measurement: coord-carry (R9 +47%), ownership transpose (R10
// +64%), 8-wave (R11 +52%), 4096-cell sort (R12 +7%), fmed3 lb (R13 +3%),
// s_setprio (R15 +1%). Bound: serial 2048-step argmax dependency, ~638
// ns/iter; not a HW roofline (HBM 0.006%, VALU 1.9%).
// ---------------------------------------------------------------------------
__global__ __launch_bounds__(FPS_T) void fps_kernel(const float* __restrict__ xyz,
                                                    float* __restrict__ new_xyz) {
  __shared__ float sx[N_PTS], sy[N_PTS], sz[N_PTS];
  __shared__ int perm[N_PTS];          // setup only; reused as cent[] in loop
  __shared__ uint32_t bins[NBINS];
  __shared__ double pkey[2][NWAVE];
  float* cent = (float*)perm;          // [NPOINT*3] = 24 KB < 32 KB

  const int b = blockIdx.x;
  const int t = threadIdx.x;
  const int lane = t & 63;
  const int w = t >> 6;
  const float* xb = xyz + (size_t)b * N_PTS * 3;

  // ---- setup: stage coords ----
  for (int e = t; e < N_PTS * 3; e += FPS_T) {
    float v = xb[e];
    int p = e / 3, c = e - 3 * p;
    if (c == 0) sx[p] = v;
    else if (c == 1) sy[p] = v;
    else sz[p] = v;
  }
  if (t < NBINS) bins[t] = 0;
  __syncthreads();

  // ---- counting sort by morton cell: histogram ----
#pragma unroll
  for (int k = 0; k < CH; ++k) {
    int p = k * FPS_T + t;
    atomicAdd(&bins[cell_of(sx[p], sy[p], sz[p])], 1u);
  }
  __syncthreads();

  // ---- exclusive scan of 512 bins (wave 0, in place) ----
  if (t < 64) {
    uint32_t v[8], e[8], run = 0;
#pragma unroll
    for (int j = 0; j < 8; ++j) v[j] = bins[t * 8 + j];
#pragma unroll
    for (int j = 0; j < 8; ++j) { e[j] = run; run += v[j]; }
    uint32_t inc = run;
#pragma unroll
    for (int off = 1; off < 64; off <<= 1) {
      uint32_t o = __shfl_up(inc, off, 64);
      if (t >= off) inc += o;
    }
    uint32_t base = inc - run;
#pragma unroll
    for (int j = 0; j < 8; ++j) bins[t * 8 + j] = base + e[j];
  }
  __syncthreads();

  // ---- scatter permutation ----
#pragma unroll
  for (int k = 0; k < CH; ++k) {
    int p = k * FPS_T + t;
    uint32_t pos = atomicAdd(&bins[cell_of(sx[p], sy[p], sz[p])], 1u);
    perm[pos] = p;
  }
  __syncthreads();

  // ---- load chunk into registers (c = t: Morton-concentrated), bbox ----
  float rx[CH], ry[CH], rz[CH], dist[CH];
  uint32_t ridx[CH];
#pragma unroll
  for (int j = 0; j < CH; ++j) {
    int p = perm[CH * t + j];
    ridx[j] = (uint32_t)p;
    rx[j] = sx[p]; ry[j] = sy[p]; rz[j] = sz[p];
    dist[j] = __builtin_inff();
  }
  float bnx = rx[0], bxx = rx[0], bny = ry[0], bxy = ry[0], bnz = rz[0], bxz = rz[0];
#pragma unroll
  for (int j = 1; j < CH; ++j) {
    bnx = fminf(bnx, rx[j]); bxx = fmaxf(bxx, rx[j]);
    bny = fminf(bny, ry[j]); bxy = fmaxf(bxy, ry[j]);
    bnz = fminf(bnz, rz[j]); bxz = fmaxf(bxz, rz[j]);
  }
  __syncthreads();   // perm fully consumed; cent alias is now safe

  float cmax = __builtin_inff();   // chunk max dist (cached)
  uint32_t cidx = 0;               // chunk argmax orig idx (cached)
  double wkey = 0.0;               // cached wave-reduced key (lane 63 valid)
  int far = 0;

  for (int it = 0; it < NPOINT; ++it) {
    float cx = sx[far], cy = sy[far], cz = sz[far];
    if (t == 0) {   // LDS staging only -- no global store in the loop
      cent[it * 3 + 0] = cx;
      cent[it * 3 + 1] = cy;
      cent[it * 3 + 2] = cz;
    }

    // conservative lower bound of any d2 in this chunk (margin 1e-5 >> fp err)
    float gx = fmaxf(fmaxf(bnx - cx, cx - bxx), 0.0f);
    float gy = fmaxf(fmaxf(bny - cy, cy - bxy), 0.0f);
    float gz = fmaxf(fmaxf(bnz - cz, cz - bxz), 0.0f);
    float lb = gx * gx + gy * gy + gz * gz;

    bool act = !(lb * 0.99999f >= cmax);
    uint64_t am = __ballot(act);
    if (am != 0) {     // wave-uniform: some lane's cached key changes
      if (act) {
        {
#pragma clang fp contract(off)
#pragma unroll
          for (int j = 0; j < CH; ++j) {
            float dx = rx[j] - cx;
            float a = dx * dx;
            float dy = ry[j] - cy;
            a = a + dy * dy;         // exact left-to-right, no FMA
            float dz = rz[j] - cz;
            a = a + dz * dz;
            dist[j] = fminf(dist[j], a);
          }
        }
        // chunk max (tree) + first-occurrence (min orig idx) tie resolution
        float m0 = fmaxf(dist[0], dist[1]), m1 = fmaxf(dist[2], dist[3]);
        float m2 = fmaxf(dist[4], dist[5]), m3 = fmaxf(dist[6], dist[7]);
        cmax = fmaxf(fmaxf(m0, m1), fmaxf(m2, m3));
        uint32_t mi = 0xFFFFFFFFu;
#pragma unroll
        for (int j = 0; j < CH; ++j) {
          uint32_t cand = ridx[j] < mi ? ridx[j] : mi;
          mi = (dist[j] == cmax) ? cand : mi;
        }
        cidx = mi;
      }
      // wave reduce over ALL lanes' cached keys (active lanes just updated)
      double key = __builtin_bit_cast(double,
          ((uint64_t)__builtin_bit_cast(uint32_t, cmax) << 32) |
          (uint64_t)(0xFFFFFFFFu - cidx));
      DPP_MAXD(key, 0x111);   // row_shr 1
      DPP_MAXD(key, 0x112);   // row_shr 2
      DPP_MAXD(key, 0x114);   // row_shr 4
      DPP_MAXD(key, 0x118);   // row_shr 8
      DPP_MAXD(key, 0x142);   // row_bcast 15
      DPP_MAXD(key, 0x143);   // row_bcast 31  -> lane 63 has wave max
      wkey = key;             // cache (lane 63's copy is the wave max)
    }
    if (lane == 63) pkey[it & 1][w] = wkey;
    __syncthreads();

    // lane-parallel cross-wave reduce: lane reads slot (lane&15); 4-step DPP
    // row-reduce puts the max of all 16 slots in lane 15 of every row.
    double g = pkey[it & 1][lane & 15];
    DPP_MAXD(g, 0x111);
    DPP_MAXD(g, 0x112);
    DPP_MAXD(g, 0x114);
    DPP_MAXD(g, 0x118);
    uint64_t gu = __builtin_bit_cast(uint64_t, g);
    uint32_t glo = (uint32_t)__builtin_amdgcn_readlane((int)(uint32_t)gu, 15);
    far = (int)(0xFFFFFFFFu - glo);
  }

  // ---- one-time coalesced copy-out of staged centroids ----
  __syncthreads();
  float* ob = new_xyz + (size_t)b * NPOINT * 3;
  for (int e = t; e < NPOINT * 3; e += FPS_T) ob[e] = cent[e];
}

// ---------------------------------------------------------------------------
// Ball query + gather + concat, one wave per query (R14-verified, float2
// stores, bit-identical output).
// ---------------------------------------------------------------------------
__global__ __launch_bounds__(256) void ball_group_kernel(const float* __restrict__ xyz,
                                                         const float* __restrict__ points,
                                                         const float* __restrict__ new_xyz,
                                                         float* __restrict__ out_np) {
  __shared__ int list[4][NSAMPLE];
  const int wslot = threadIdx.x >> 6;
  const int lane = threadIdx.x & 63;
  const int qg = blockIdx.x * 4 + wslot;
  const int b = qg >> 11;

  const float* xb = xyz + (size_t)b * N_PTS * 3;
  const float* nq = new_xyz + (size_t)qg * 3;
  const float cqx = nq[0], cqy = nq[1], cqz = nq[2];

  int K = 0;
  {
#pragma clang fp contract(off)
    for (int c = 0; c < N_PTS / 64; ++c) {
      const int pt = c * 64 + lane;
      const float* p = xb + pt * 3;
      float dx = cqx - p[0];
      float dy = cqy - p[1];
      float dz = cqz - p[2];
      float d2 = dx * dx;
      d2 = d2 + dy * dy;
      d2 = d2 + dz * dz;
      bool in = d2 < R2;
      unsigned long long mask = __ballot(in);
      if (in) {
        int rank = __builtin_amdgcn_mbcnt_hi((uint32_t)(mask >> 32),
                     __builtin_amdgcn_mbcnt_lo((uint32_t)mask, 0));
        int s = K + rank;
        if (s < NSAMPLE) list[wslot][s] = pt;
      }
      K += (int)__popcll(mask);
      if (K >= NSAMPLE) break;   // wave-uniform
    }
  }
  __builtin_amdgcn_wave_barrier();
  int Kc = K < NSAMPLE ? K : NSAMPLE;
  int first = list[wslot][0];
  if (lane >= Kc && lane < NSAMPLE) list[wslot][lane] = first;
  __builtin_amdgcn_wave_barrier();

  const float* pb = points + (size_t)b * N_PTS * C_FEAT;
  float* oq = out_np + (size_t)qg * (NSAMPLE * 67);
#pragma unroll
  for (int r = 0; r < 17; ++r) {
    int pp = r * 64 + lane;                 // float2 index, 0..1071 valid
    if (pp < (NSAMPLE * 67) / 2) {
      int e0 = pp * 2;
      int s0 = e0 / 67;
      int f0 = e0 - s0 * 67;
      int s1 = (f0 == 66) ? s0 + 1 : s0;    // e1 = e0+1 may cross slot
      int f1 = (f0 == 66) ? 0 : f0 + 1;
      int i0 = list[wslot][s0];
      int i1 = list[wslot][s1];
      float v0, v1;
      if (f0 < 3) {
        float cf = (f0 == 0) ? cqx : ((f0 == 1) ? cqy : cqz);
        v0 = xb[i0 * 3 + f0] - cf;
      } else {
        v0 = pb[(size_t)i0 * C_FEAT + (f0 - 3)];
      }
      if (f1 < 3) {
        float cf = (f1 == 0) ? cqx : ((f1 == 1) ? cqy : cqz);
        v1 = xb[i1 * 3 + f1] - cf;
      } else {
        v1 = pb[(size_t)i1 * C_FEAT + (f1 - 3)];
      }
      *reinterpret_cast<float2*>(&oq[e0]) = make_float2(v0, v1);
    }
  }
}

extern "C" void kernel_launch(void* const* d_in, const int* in_sizes, int n_in,
                              void* d_out, int out_size, void* d_ws, size_t ws_size,
                              hipStream_t stream) {
  const float* xyz = (const float*)d_in[0];
  const float* points = (const float*)d_in[1];
  float* out = (float*)d_out;
  float* new_xyz = out;
  float* new_points = out + (size_t)N_BATCH * NPOINT * 3;

  fps_kernel<<<N_BATCH, FPS_T, 0, stream>>>(xyz, new_xyz);
  ball_group_kernel<<<(N_BATCH * NPOINT) / 4, 256, 0, stream>>>(xyz, points, new_xyz, new_points);
}